// Round 17
// baseline (48.275 us; speedup 1.0000x reference)
//
#include <hip/hip_runtime.h>
#include <math.h>

#define B 4
#define NBC 128
#define HID 64
#define HC 64
#define WC 64
#define P_TOTAL (HC*WC)
#define HOUT 256
#define WOUT 256
#define NSPLIT 4
#define NQ (NBC/NSPLIT)          // 32 boundary points per block

typedef __attribute__((ext_vector_type(8)))  _Float16 h8;    // f16 MFMA A/B frag
typedef __attribute__((ext_vector_type(2)))  _Float16 h2v;   // fdot2 operand
typedef __attribute__((ext_vector_type(4)))  unsigned u32x4; // packed f16 pairs
typedef __attribute__((ext_vector_type(16))) float    fx16;  // 32x32 MFMA C/D frag
typedef __attribute__((ext_vector_type(2)))  float    f32x2; // v_pk_*_f32 pair

// Fast exact-gelu: erf via 3-term Abramowitz-Stegun 7.1.25 (|err| <= 2.5e-5).
__device__ __forceinline__ float gelu_fast(float x) {
    float y = fabsf(x) * 0.70710678118654752f;
    float t = __builtin_amdgcn_rcpf(fmaf(0.47047f, y, 1.0f));
    float p = fmaf(t, 0.7478556f, -0.0958798f);
    p = fmaf(t, p, 0.3480242f);
    p = p * t;
    float e = __expf(-y * y);
    float er = fmaf(-p, e, 1.0f);
    float s = copysignf(er, x);
    float hx = 0.5f * x;
    return fmaf(hx, s, hx);
}

// ---------------------------------------------------------------------------
// Kernel A (fused prep): 64-thread blocks, partitioned by blockIdx.x:
//   [0,512)        : boundary encoder -> bfg (pre-scaled x128)
//   [512,514)      : gelu LUT -> lutg: 4096 f16 nodes at INTEGER index
//                    positions over [-16,16)
//   [514,514+1024) : cg table -> cg_g = cg*128 + 2048 + 2^22  (magic domain)
// ---------------------------------------------------------------------------
__global__ void bg_prep(const float* __restrict__ bi,
                        const float* __restrict__ e1w, const float* __restrict__ e1b,
                        const float* __restrict__ e2w, const float* __restrict__ e2b,
                        const float* __restrict__ g1w, const float* __restrict__ g1b,
                        float* __restrict__ bfg,
                        unsigned short* __restrict__ lutg,
                        float* __restrict__ cg_g) {
    const int blk = blockIdx.x;
    const int t   = threadIdx.x;          // 0..63
    if (blk < 512) {                      // ---- encoder ----
        int bn = blk, h = t;
        __shared__ float t1[HID];
        __shared__ float t2[HID];
        float x = bi[bn*3+0], y = bi[bn*3+1], z = bi[bn*3+2];
        float a = x*e1w[0*HID+h] + y*e1w[1*HID+h] + z*e1w[2*HID+h] + e1b[h];
        t1[h] = gelu_fast(a);
        __syncthreads();
        float s = e2b[h];
        #pragma unroll
        for (int k = 0; k < HID; ++k) s += t1[k]*e2w[k*HID+h];
        t2[h] = gelu_fast(s);
        __syncthreads();
        float o = g1b[h];
        #pragma unroll
        for (int k = 0; k < HID; ++k) o += t2[k]*g1w[k*HID+h];
        bfg[bn*HID+h] = o * 128.0f;       // pre-scaled for LUT indexing
    } else if (blk < 514) {               // ---- gelu LUT (f16 bits, int nodes) ----
        int base = (blk - 512) * 2048;
        #pragma unroll
        for (int r = 0; r < 32; ++r) {
            int idx = base + t + r*64;
            float node = fmaf((float)idx, 0.0078125f, -16.0f);   // -16 + i/128
            _Float16 hv = (_Float16)gelu_fast(node);             // RNE
            lutg[idx] = __builtin_bit_cast(unsigned short, hv);
        }
    } else {                              // ---- cg table (magic domain) ----
        int pgrp = blk - 514;             // 4 p's per block
        #pragma unroll
        for (int r = 0; r < 4; ++r) {
            int i = t + r*64;             // 0..255
            int p = pgrp*4 + (i >> 6);
            int k = i & 63;
            float gxx = -1.0f + (2.0f/(WC-1)) * (float)(p & (WC-1));
            float gyy = -1.0f + (2.0f/(HC-1)) * (float)(p >> 6);
            cg_g[p*HID + k] = fmaf(gxx*g1w[64*HID+k] + gyy*g1w[65*HID+k],
                                   128.0f, 4196352.0f);          // 2048 + 2^22
        }
    }
}

// ---------------------------------------------------------------------------
// Kernel B: main contraction. Grid (128 p-tiles, B, 4 n-quarters), block 256.
// Swapped fp16 MFMA D[j][p], lane's C column = p = lane&31. Dual-n ILP.
// r17 — decisive pipe-split test: h1 gathers m=0,1 from LDS, m=2,3 from
// global L1 (loads independent of m=0,1 MFMAs -> issued early, latency
// hidden); h2 gathers global (r16); cg slice hoisted to 32 VGPRs. LDS
// gather instrs per dual-iter: 96 (r15) -> 32. If this is neutral, the
// kernel is dependency-latency-bound at the 4-waves/SIMD VGPR granule
// (m69: 8 waves needs <=64 VGPR — impossible with dual 16-reg accs) and
// the algorithm shape is at its floor. VGPR ~116 < 128 granule.
// Never force occupancy via launch_bounds (r4/r12: spill).
// ---------------------------------------------------------------------------
__global__ __launch_bounds__(256, 2) void bg_main(
    const float* __restrict__ bi,
    const float* __restrict__ g1w,     // row 66 = g1w_d
    const float* __restrict__ g2w,     // [64][32]
    const float* __restrict__ g2b,     // [32]
    const float* __restrict__ g3w,     // [32]
    const float* __restrict__ g3b,     // [1]
    const float* __restrict__ dscale,  // [1]
    const float* __restrict__ bfg,     // [B*NBC][HID], pre-scaled x128
    const unsigned short* __restrict__ lutg,  // [4096] f16-bits gelu
    const float* __restrict__ cg_g,    // [P_TOTAL][HID] magic-domain cg
    float* __restrict__ ucp)           // [NSPLIT][B][P_TOTAL] partials
{
    const int b    = blockIdx.y;
    const int nh   = blockIdx.z;       // n-quarter: 0..3
    const int p0   = blockIdx.x * 32;
    const int tid  = threadIdx.x;
    const int lane = tid & 63;
    const int wid  = tid >> 6;         // 0..3
    const int row  = lane & 31;        // p column of C
    const int half = lane >> 5;        // k/j sub-block

    __shared__ float s_bfg[NQ][HID];           // 8 KB (x128 pre-scaled)
    __shared__ float s_cg[32][66];             // 8.25 KB, magic domain (staging)
    __shared__ unsigned short s_lut16[4096];   // 8 KB f16 gelu (h1 m=0,1 path)
    __shared__ float s_bcx[NQ], s_bcy[NQ];
    __shared__ float s_g1d[HID];               // g1d*128
    __shared__ float s_red[4][32];

    {   // stage this n-quarter's bfg rows (512 float4 / 256 thr)
        const float4* src = (const float4*)(bfg + (b*NBC + nh*NQ)*HID);
        float4* dst = (float4*)(&s_bfg[0][0]);
        dst[tid]       = src[tid];
        dst[tid + 256] = src[tid + 256];
    }
    {   // stage the LUT (8 KB): 512 uint4
        const uint4* src = (const uint4*)lutg;
        uint4* dst = (uint4*)s_lut16;
        dst[tid]       = src[tid];
        dst[tid + 256] = src[tid + 256];
    }
    {   // stage cg slice (8 KB) coalesced into padded [32][66]
        const float4* src = (const float4*)(cg_g + p0*HID);
        #pragma unroll
        for (int i = 0; i < 2; ++i) {
            int idx = tid + i*256;            // 512 float4
            float4 v = src[idx];
            int pl = idx >> 4;                // 16 float4 per row
            int kq = (idx & 15) * 4;
            float2* d = (float2*)&s_cg[pl][kq];   // 8B-aligned (stride 66)
            d[0] = float2{v.x, v.y};
            d[1] = float2{v.z, v.w};
        }
    }
    if (tid < NQ) {
        int ng = b*NBC + nh*NQ + tid;
        s_bcx[tid] = bi[ng*3+0];
        s_bcy[tid] = bi[ng*3+1];
    }
    if (tid >= 64 && tid < 128)  s_g1d[tid-64] = g1w[66*HID + (tid-64)] * 128.0f;

    // hoisted per-lane constants (VGPRs): bias 16 f32, g3w 8 packed f16
    float4 biasv[4];
    unsigned g3p[8];
    #pragma unroll
    for (int rr = 0; rr < 4; ++rr) {
        biasv[rr] = *(const float4*)&g2b[rr*8 + half*4];
        float4 gwf = *(const float4*)&g3w[rr*8 + half*4];
        unsigned lo0 = (unsigned)__builtin_bit_cast(unsigned short, (_Float16)gwf.x);
        unsigned hi0 = (unsigned)__builtin_bit_cast(unsigned short, (_Float16)gwf.y);
        unsigned lo1 = (unsigned)__builtin_bit_cast(unsigned short, (_Float16)gwf.z);
        unsigned hi1 = (unsigned)__builtin_bit_cast(unsigned short, (_Float16)gwf.w);
        g3p[rr*2+0] = lo0 | (hi0 << 16);
        g3p[rr*2+1] = lo1 | (hi1 << 16);
    }

    // g2w^T fragments (A operand) in fp16 (rel err 2^-11)
    h8 wf[4];
    #pragma unroll
    for (int m = 0; m < 4; ++m) {
        #pragma unroll
        for (int e = 0; e < 8; ++e) {
            int k = m*16 + half*8 + e;
            wf[m][e] = (_Float16)g2w[k*32 + row];
        }
    }
    __syncthreads();

    // hoist this lane's cg slice into VGPRs (32 f32) — frees 8 LDS b128/iter
    f32x2 cgv[16];
    #pragma unroll
    for (int m = 0; m < 4; ++m) {
        #pragma unroll
        for (int pr = 0; pr < 4; ++pr)
            cgv[m*4+pr] = *(const f32x2*)&s_cg[row][m*16 + half*8 + 2*pr];
    }

    const int p = p0 + row;
    const float gx = -1.0f + (2.0f/(WC-1)) * (float)(p & (WC-1));
    const float gy = -1.0f + (2.0f/(HC-1)) * (float)(p >> 6);
    const float as = fabsf(dscale[0]);
    const float g3bias = g3b[0];

    const f32x2 kScale2 = {128.0f, 128.0f};
    const f32x2 kOffM2  = {4196352.0f, 4196352.0f};   // 2048 + 2^22
    const char* lutb = (const char*)lutg;              // global base (L1-resident)

    float accp = 0.0f, wsum = 0.0f;

    for (int ni = 0; ni < 4; ++ni) {
        const int nA = wid*8 + 2*ni;
        const int nB = nA + 1;
        float dxA = s_bcx[nA] - gx, dyA = s_bcy[nA] - gy;
        float dxB = s_bcx[nB] - gx, dyB = s_bcy[nB] - gy;
        float distA = sqrtf(fmaf(dxA, dxA, fmaf(dyA, dyA, 1e-8f)));
        float distB = sqrtf(fmaf(dxB, dxB, fmaf(dyB, dyB, 1e-8f)));
        float wgtA = __expf(-as * distA);
        float wgtB = __expf(-as * distB);
        wsum += wgtA + wgtB;
        f32x2 distA2 = {distA, distA};
        f32x2 distB2 = {distB, distB};

        fx16 accA, accB;                 // two independent 4-deep MFMA chains
        #pragma unroll
        for (int rr = 0; rr < 4; ++rr) {
            accA[rr*4+0] = biasv[rr].x; accA[rr*4+1] = biasv[rr].y;
            accA[rr*4+2] = biasv[rr].z; accA[rr*4+3] = biasv[rr].w;
            accB[rr*4+0] = biasv[rr].x; accB[rr*4+1] = biasv[rr].y;
            accB[rr*4+2] = biasv[rr].z; accB[rr*4+3] = biasv[rr].w;
        }

        #pragma unroll
        for (int m = 0; m < 4; ++m) {
            const int kb = m*16 + half*8;
            const f32x2* bfgA2 = (const f32x2*)&s_bfg[nA][kb];
            const f32x2* bfgB2 = (const f32x2*)&s_bfg[nB][kb];
            const f32x2* g1d2  = (const f32x2*)&s_g1d[kb];
            u32x4 afA, afB;
            #pragma unroll
            for (int pr = 0; pr < 4; ++pr) {
                f32x2 base = cgv[m*4+pr];        // magic-domain cg (VGPR)
                f32x2 gd   = g1d2[pr];
                f32x2 zA = bfgA2[pr] + (distA2 * gd + base);   // pk_fma + pk_add
                f32x2 zB = bfgB2[pr] + (distB2 * gd + base);
                unsigned oA0 = __float_as_uint(zA.x) & 0x1FFEu;  // mask is OOB-safe
                unsigned oA1 = __float_as_uint(zA.y) & 0x1FFEu;
                unsigned oB0 = __float_as_uint(zB.x) & 0x1FFEu;
                unsigned oB1 = __float_as_uint(zB.y) & 0x1FFEu;
                unsigned vA0, vA1, vB0, vB1;
                if (m < 2) {                     // LDS pipe
                    vA0 = *(const unsigned short*)((const char*)s_lut16 + oA0);
                    vA1 = *(const unsigned short*)((const char*)s_lut16 + oA1);
                    vB0 = *(const unsigned short*)((const char*)s_lut16 + oB0);
                    vB1 = *(const unsigned short*)((const char*)s_lut16 + oB1);
                } else {                         // VMEM pipe (L1-resident 8KB)
                    vA0 = *(const unsigned short*)(lutb + oA0);
                    vA1 = *(const unsigned short*)(lutb + oA1);
                    vB0 = *(const unsigned short*)(lutb + oB0);
                    vB1 = *(const unsigned short*)(lutb + oB1);
                }
                afA[pr] = vA0 | (vA1 << 16);
                afB[pr] = vB0 | (vB1 << 16);
            }
            accA = __builtin_amdgcn_mfma_f32_32x32x16_f16(wf[m], __builtin_bit_cast(h8, afA), accA, 0, 0, 0);
            accB = __builtin_amdgcn_mfma_f32_32x32x16_f16(wf[m], __builtin_bit_cast(h8, afB), accB, 0, 0, 0);
        }

        // epilogue: gelu(h2) via GLOBAL (L1) LUT gathers, fdot2 with hoisted g3w
        float sA = 0.0f, sB = 0.0f;
        #pragma unroll
        for (int rr = 0; rr < 4; ++rr) {
            #pragma unroll
            for (int qq = 0; qq < 4; qq += 2) {
                h2v gw2 = __builtin_bit_cast(h2v, g3p[rr*2 + (qq >> 1)]);
                f32x2 hA = {accA[rr*4+qq], accA[rr*4+qq+1]};
                f32x2 zA = hA * kScale2 + kOffM2;
                unsigned oA0 = __float_as_uint(zA.x) & 0x1FFEu;
                unsigned oA1 = __float_as_uint(zA.y) & 0x1FFEu;
                unsigned vA0 = *(const unsigned short*)(lutb + oA0);   // global L1
                unsigned vA1 = *(const unsigned short*)(lutb + oA1);
                sA = __builtin_amdgcn_fdot2(__builtin_bit_cast(h2v, vA0 | (vA1 << 16)), gw2, sA, false);
                f32x2 hB = {accB[rr*4+qq], accB[rr*4+qq+1]};
                f32x2 zB = hB * kScale2 + kOffM2;
                unsigned oB0 = __float_as_uint(zB.x) & 0x1FFEu;
                unsigned oB1 = __float_as_uint(zB.y) & 0x1FFEu;
                unsigned vB0 = *(const unsigned short*)(lutb + oB0);
                unsigned vB1 = *(const unsigned short*)(lutb + oB1);
                sB = __builtin_amdgcn_fdot2(__builtin_bit_cast(h2v, vB0 | (vB1 << 16)), gw2, sB, false);
            }
        }
        accp = fmaf(sA, wgtA, fmaf(sB, wgtB, accp));
    }

    // combine the two j-halves (lane and lane^32 share the same p)
    float v = accp + __shfl_xor(accp, 32, 64);
    if (half == 0) s_red[wid][row] = fmaf(g3bias, wsum, v);
    __syncthreads();
    if (tid < 32) {
        float sum = s_red[0][tid] + s_red[1][tid] + s_red[2][tid] + s_red[3][tid];
        ucp[(nh*B + b)*P_TOTAL + p0 + tid] = sum * (1.0f/NBC);
    }
}

// ---------------------------------------------------------------------------
// Kernel C: combine n-quarter partials + bilinear align_corners upsample
// ---------------------------------------------------------------------------
__global__ void bg_upsample(const float* __restrict__ ucp, float* __restrict__ out) {
    int idx = blockIdx.x * 256 + threadIdx.x;
    if (idx >= B*HOUT*WOUT) return;
    int x = idx & (WOUT-1);
    int y = (idx >> 8) & (HOUT-1);
    int b = idx >> 16;
    float fy = (float)y * ((float)(HC-1)/(float)(HOUT-1));
    float fx = (float)x * ((float)(WC-1)/(float)(WOUT-1));
    int y0 = (int)floorf(fy);
    int x0 = (int)floorf(fx);
    int y1 = min(y0+1, HC-1);
    int x1 = min(x0+1, WC-1);
    float wy = fy - (float)y0;
    float wx = fx - (float)x0;
    float v00 = 0.0f, v01 = 0.0f, v10 = 0.0f, v11 = 0.0f;
    #pragma unroll
    for (int q = 0; q < NSPLIT; ++q) {
        const float* u = ucp + (q*B + b)*P_TOTAL;
        v00 += u[y0*WC+x0];
        v01 += u[y0*WC+x1];
        v10 += u[y1*WC+x0];
        v11 += u[y1*WC+x1];
    }
    float top = v00 + (v01 - v00)*wx;
    float bot = v10 + (v11 - v10)*wx;
    out[idx] = top + (bot - top)*wy;
}

extern "C" void kernel_launch(void* const* d_in, const int* in_sizes, int n_in,
                              void* d_out, int out_size, void* d_ws, size_t ws_size,
                              hipStream_t stream) {
    const float* bi  = (const float*)d_in[0];
    const float* e1w = (const float*)d_in[2];
    const float* e1b = (const float*)d_in[3];
    const float* e2w = (const float*)d_in[4];
    const float* e2b = (const float*)d_in[5];
    const float* g1w = (const float*)d_in[6];
    const float* g1b = (const float*)d_in[7];
    const float* g2w = (const float*)d_in[8];
    const float* g2b = (const float*)d_in[9];
    const float* g3w = (const float*)d_in[10];
    const float* g3b = (const float*)d_in[11];
    const float* ds  = (const float*)d_in[12];
    float* out = (float*)d_out;

    float* bfg = (float*)d_ws;                          // 128 KB (x128 scaled)
    float* ucp = bfg + B*NBC*HID;                       // 256 KB partials
    unsigned short* lutg = (unsigned short*)(ucp + NSPLIT*B*P_TOTAL);  // 8 KB
    float* cg_g = (float*)(lutg + 4096);                // 1 MB cg table

    bg_prep<<<dim3(514 + P_TOTAL/4), dim3(64), 0, stream>>>(
        bi, e1w, e1b, e2w, e2b, g1w, g1b, bfg, lutg, cg_g);
    bg_main<<<dim3(P_TOTAL/32, B, NSPLIT), dim3(256), 0, stream>>>(
        bi, g1w, g2w, g2b, g3w, g3b, ds, bfg, lutg, cg_g, ucp);
    bg_upsample<<<dim3((B*HOUT*WOUT)/256), dim3(256), 0, stream>>>(ucp, out);
}

// Round 18
// 43.429 us; speedup vs baseline: 1.1116x; 1.1116x over previous
//
#include <hip/hip_runtime.h>
#include <math.h>

#define B 4
#define NBC 128
#define HID 64
#define HC 64
#define WC 64
#define P_TOTAL (HC*WC)
#define HOUT 256
#define WOUT 256
#define NSPLIT 4
#define NQ (NBC/NSPLIT)          // 32 boundary points per block

typedef __attribute__((ext_vector_type(8)))  _Float16 h8;    // f16 MFMA A/B frag
typedef __attribute__((ext_vector_type(2)))  _Float16 h2v;   // fdot2 operand
typedef __attribute__((ext_vector_type(4)))  unsigned u32x4; // packed f16 pairs
typedef __attribute__((ext_vector_type(16))) float    fx16;  // 32x32 MFMA C/D frag
typedef __attribute__((ext_vector_type(2)))  float    f32x2; // v_pk_*_f32 pair

// Fast exact-gelu: erf via 3-term Abramowitz-Stegun 7.1.25 (|err| <= 2.5e-5).
__device__ __forceinline__ float gelu_fast(float x) {
    float y = fabsf(x) * 0.70710678118654752f;
    float t = __builtin_amdgcn_rcpf(fmaf(0.47047f, y, 1.0f));
    float p = fmaf(t, 0.7478556f, -0.0958798f);
    p = fmaf(t, p, 0.3480242f);
    p = p * t;
    float e = __expf(-y * y);
    float er = fmaf(-p, e, 1.0f);
    float s = copysignf(er, x);
    float hx = 0.5f * x;
    return fmaf(hx, s, hx);
}

// ---------------------------------------------------------------------------
// Kernel A (fused prep): 64-thread blocks, partitioned by blockIdx.x:
//   [0,512)        : boundary encoder -> bfg (pre-scaled x128)
//   [512,514)      : gelu LUT -> lutg: 4096 f16 nodes at INTEGER index
//                    positions over [-16,16)
//   [514,514+1024) : cg table -> cg_g = cg*128 + 2048 + 2^22  (magic domain)
// ---------------------------------------------------------------------------
__global__ void bg_prep(const float* __restrict__ bi,
                        const float* __restrict__ e1w, const float* __restrict__ e1b,
                        const float* __restrict__ e2w, const float* __restrict__ e2b,
                        const float* __restrict__ g1w, const float* __restrict__ g1b,
                        float* __restrict__ bfg,
                        unsigned short* __restrict__ lutg,
                        float* __restrict__ cg_g) {
    const int blk = blockIdx.x;
    const int t   = threadIdx.x;          // 0..63
    if (blk < 512) {                      // ---- encoder ----
        int bn = blk, h = t;
        __shared__ float t1[HID];
        __shared__ float t2[HID];
        float x = bi[bn*3+0], y = bi[bn*3+1], z = bi[bn*3+2];
        float a = x*e1w[0*HID+h] + y*e1w[1*HID+h] + z*e1w[2*HID+h] + e1b[h];
        t1[h] = gelu_fast(a);
        __syncthreads();
        float s = e2b[h];
        #pragma unroll
        for (int k = 0; k < HID; ++k) s += t1[k]*e2w[k*HID+h];
        t2[h] = gelu_fast(s);
        __syncthreads();
        float o = g1b[h];
        #pragma unroll
        for (int k = 0; k < HID; ++k) o += t2[k]*g1w[k*HID+h];
        bfg[bn*HID+h] = o * 128.0f;       // pre-scaled for LUT indexing
    } else if (blk < 514) {               // ---- gelu LUT (f16 bits, int nodes) ----
        int base = (blk - 512) * 2048;
        #pragma unroll
        for (int r = 0; r < 32; ++r) {
            int idx = base + t + r*64;
            float node = fmaf((float)idx, 0.0078125f, -16.0f);   // -16 + i/128
            _Float16 hv = (_Float16)gelu_fast(node);             // RNE
            lutg[idx] = __builtin_bit_cast(unsigned short, hv);
        }
    } else {                              // ---- cg table (magic domain) ----
        int pgrp = blk - 514;             // 4 p's per block
        #pragma unroll
        for (int r = 0; r < 4; ++r) {
            int i = t + r*64;             // 0..255
            int p = pgrp*4 + (i >> 6);
            int k = i & 63;
            float gxx = -1.0f + (2.0f/(WC-1)) * (float)(p & (WC-1));
            float gyy = -1.0f + (2.0f/(HC-1)) * (float)(p >> 6);
            cg_g[p*HID + k] = fmaf(gxx*g1w[64*HID+k] + gyy*g1w[65*HID+k],
                                   128.0f, 4196352.0f);          // 2048 + 2^22
        }
    }
}

// ---------------------------------------------------------------------------
// Kernel B: main contraction. Grid (128 p-tiles, B, 4 n-quarters), block 256.
// Swapped fp16 MFMA D[j][p], lane's C column = p = lane&31. Dual-n ILP:
// two independent 4-deep MFMA chains + two gather streams fill each other's
// dependency stalls. All LUT gathers on the LDS pipe — r16/r17 proved
// scattered VMEM gathers are strictly worse (L1 serializes divergent 2B
// loads; LDS's banked gather wins). ~201M total gathers at ~5.8cyc/wave on
// 256 CUs ~= 30us = the binding pipe; this config is the measured optimum.
// Clamps dropped: &0x1FFE alone keeps the LDS offset in [0,8190] for ANY
// float bits (OOB-safe unconditionally). Never force occupancy via
// launch_bounds (r4/r12: spill).
// ---------------------------------------------------------------------------
__global__ __launch_bounds__(256, 2) void bg_main(
    const float* __restrict__ bi,
    const float* __restrict__ g1w,     // row 66 = g1w_d
    const float* __restrict__ g2w,     // [64][32]
    const float* __restrict__ g2b,     // [32]
    const float* __restrict__ g3w,     // [32]
    const float* __restrict__ g3b,     // [1]
    const float* __restrict__ dscale,  // [1]
    const float* __restrict__ bfg,     // [B*NBC][HID], pre-scaled x128
    const unsigned short* __restrict__ lutg,  // [4096] f16-bits gelu
    const float* __restrict__ cg_g,    // [P_TOTAL][HID] magic-domain cg
    float* __restrict__ ucp)           // [NSPLIT][B][P_TOTAL] partials
{
    const int b    = blockIdx.y;
    const int nh   = blockIdx.z;       // n-quarter: 0..3
    const int p0   = blockIdx.x * 32;
    const int tid  = threadIdx.x;
    const int lane = tid & 63;
    const int wid  = tid >> 6;         // 0..3
    const int row  = lane & 31;        // p column of C
    const int half = lane >> 5;        // k/j sub-block

    __shared__ float s_bfg[NQ][HID];           // 8 KB (x128 pre-scaled)
    __shared__ float s_cg[32][66];             // 8.25 KB, magic domain
    __shared__ unsigned short s_lut16[4096];   // 8 KB f16 gelu
    __shared__ float s_bcx[NQ], s_bcy[NQ];
    __shared__ float s_g1d[HID];               // g1d*128
    __shared__ float s_g2b[32];
    __shared__ unsigned s_g3h[16];             // g3w packed f16 pairs
    __shared__ float s_red[4][32];

    {   // stage this n-quarter's bfg rows (512 float4 / 256 thr)
        const float4* src = (const float4*)(bfg + (b*NBC + nh*NQ)*HID);
        float4* dst = (float4*)(&s_bfg[0][0]);
        dst[tid]       = src[tid];
        dst[tid + 256] = src[tid + 256];
    }
    {   // stage the LUT (8 KB): 512 uint4
        const uint4* src = (const uint4*)lutg;
        uint4* dst = (uint4*)s_lut16;
        dst[tid]       = src[tid];
        dst[tid + 256] = src[tid + 256];
    }
    {   // stage cg slice (8 KB) from global table into padded [32][66]
        const float4* src = (const float4*)(cg_g + p0*HID);
        #pragma unroll
        for (int i = 0; i < 2; ++i) {
            int idx = tid + i*256;            // 512 float4
            float4 v = src[idx];
            int pl = idx >> 4;                // 16 float4 per row
            int kq = (idx & 15) * 4;
            float2* d = (float2*)&s_cg[pl][kq];   // 8B-aligned (stride 66)
            d[0] = float2{v.x, v.y};
            d[1] = float2{v.z, v.w};
        }
    }
    if (tid < NQ) {
        int ng = b*NBC + nh*NQ + tid;
        s_bcx[tid] = bi[ng*3+0];
        s_bcy[tid] = bi[ng*3+1];
    }
    if (tid >= 64 && tid < 128)  s_g1d[tid-64] = g1w[66*HID + (tid-64)] * 128.0f;
    if (tid >= 128 && tid < 160) s_g2b[tid-128] = g2b[tid-128];
    if (tid >= 160 && tid < 176) {
        int j = (tid-160)*2;
        unsigned lo = (unsigned)__builtin_bit_cast(unsigned short, (_Float16)g3w[j]);
        unsigned hi = (unsigned)__builtin_bit_cast(unsigned short, (_Float16)g3w[j+1]);
        s_g3h[tid-160] = lo | (hi << 16);
    }

    // g2w^T fragments (A operand) in fp16 (rel err 2^-11)
    h8 wf[4];
    #pragma unroll
    for (int m = 0; m < 4; ++m) {
        #pragma unroll
        for (int e = 0; e < 8; ++e) {
            int k = m*16 + half*8 + e;
            wf[m][e] = (_Float16)g2w[k*32 + row];
        }
    }
    __syncthreads();

    const int p = p0 + row;
    const float gx = -1.0f + (2.0f/(WC-1)) * (float)(p & (WC-1));
    const float gy = -1.0f + (2.0f/(HC-1)) * (float)(p >> 6);
    const float as = fabsf(dscale[0]);
    const float g3bias = g3b[0];

    const f32x2 kScale2 = {128.0f, 128.0f};
    const f32x2 kOffM2  = {4196352.0f, 4196352.0f};   // 2048 + 2^22

    float accp = 0.0f, wsum = 0.0f;

    for (int ni = 0; ni < 4; ++ni) {
        const int nA = wid*8 + 2*ni;
        const int nB = nA + 1;
        float dxA = s_bcx[nA] - gx, dyA = s_bcy[nA] - gy;
        float dxB = s_bcx[nB] - gx, dyB = s_bcy[nB] - gy;
        float distA = sqrtf(fmaf(dxA, dxA, fmaf(dyA, dyA, 1e-8f)));
        float distB = sqrtf(fmaf(dxB, dxB, fmaf(dyB, dyB, 1e-8f)));
        float wgtA = __expf(-as * distA);
        float wgtB = __expf(-as * distB);
        wsum += wgtA + wgtB;
        f32x2 distA2 = {distA, distA};
        f32x2 distB2 = {distB, distB};

        fx16 accA, accB;                 // two independent 4-deep MFMA chains
        #pragma unroll
        for (int rr = 0; rr < 4; ++rr) {
            float4 bias = *(const float4*)&s_g2b[rr*8 + half*4];
            accA[rr*4+0] = bias.x; accA[rr*4+1] = bias.y;
            accA[rr*4+2] = bias.z; accA[rr*4+3] = bias.w;
            accB[rr*4+0] = bias.x; accB[rr*4+1] = bias.y;
            accB[rr*4+2] = bias.z; accB[rr*4+3] = bias.w;
        }

        #pragma unroll
        for (int m = 0; m < 4; ++m) {
            const int kb = m*16 + half*8;
            const f32x2* bfgA2 = (const f32x2*)&s_bfg[nA][kb];
            const f32x2* bfgB2 = (const f32x2*)&s_bfg[nB][kb];
            const f32x2* g1d2  = (const f32x2*)&s_g1d[kb];
            const f32x2* cg2   = (const f32x2*)&s_cg[row][kb];
            u32x4 afA, afB;
            #pragma unroll
            for (int pr = 0; pr < 4; ++pr) {
                f32x2 base = cg2[pr];            // magic-domain cg
                f32x2 gd   = g1d2[pr];
                f32x2 zA = bfgA2[pr] + (distA2 * gd + base);   // pk_fma + pk_add
                f32x2 zB = bfgB2[pr] + (distB2 * gd + base);
                unsigned oA0 = __float_as_uint(zA.x) & 0x1FFEu;  // mask is OOB-safe
                unsigned oA1 = __float_as_uint(zA.y) & 0x1FFEu;
                unsigned oB0 = __float_as_uint(zB.x) & 0x1FFEu;
                unsigned oB1 = __float_as_uint(zB.y) & 0x1FFEu;
                unsigned vA0 = *(const unsigned short*)((const char*)s_lut16 + oA0);
                unsigned vA1 = *(const unsigned short*)((const char*)s_lut16 + oA1);
                unsigned vB0 = *(const unsigned short*)((const char*)s_lut16 + oB0);
                unsigned vB1 = *(const unsigned short*)((const char*)s_lut16 + oB1);
                afA[pr] = vA0 | (vA1 << 16);
                afB[pr] = vB0 | (vB1 << 16);
            }
            accA = __builtin_amdgcn_mfma_f32_32x32x16_f16(wf[m], __builtin_bit_cast(h8, afA), accA, 0, 0, 0);
            accB = __builtin_amdgcn_mfma_f32_32x32x16_f16(wf[m], __builtin_bit_cast(h8, afB), accB, 0, 0, 0);
        }

        // epilogue: gelu(h2) via magic-index LUT, fdot2 with packed-f16 g3w
        float sA = 0.0f, sB = 0.0f;
        #pragma unroll
        for (int rr = 0; rr < 4; ++rr) {
            #pragma unroll
            for (int qq = 0; qq < 4; qq += 2) {
                h2v gw2 = __builtin_bit_cast(h2v, s_g3h[rr*4 + half*2 + (qq >> 1)]);
                f32x2 hA = {accA[rr*4+qq], accA[rr*4+qq+1]};
                f32x2 zA = hA * kScale2 + kOffM2;
                unsigned oA0 = __float_as_uint(zA.x) & 0x1FFEu;
                unsigned oA1 = __float_as_uint(zA.y) & 0x1FFEu;
                unsigned vA0 = *(const unsigned short*)((const char*)s_lut16 + oA0);
                unsigned vA1 = *(const unsigned short*)((const char*)s_lut16 + oA1);
                sA = __builtin_amdgcn_fdot2(__builtin_bit_cast(h2v, vA0 | (vA1 << 16)), gw2, sA, false);
                f32x2 hB = {accB[rr*4+qq], accB[rr*4+qq+1]};
                f32x2 zB = hB * kScale2 + kOffM2;
                unsigned oB0 = __float_as_uint(zB.x) & 0x1FFEu;
                unsigned oB1 = __float_as_uint(zB.y) & 0x1FFEu;
                unsigned vB0 = *(const unsigned short*)((const char*)s_lut16 + oB0);
                unsigned vB1 = *(const unsigned short*)((const char*)s_lut16 + oB1);
                sB = __builtin_amdgcn_fdot2(__builtin_bit_cast(h2v, vB0 | (vB1 << 16)), gw2, sB, false);
            }
        }
        accp = fmaf(sA, wgtA, fmaf(sB, wgtB, accp));
    }

    // combine the two j-halves (lane and lane^32 share the same p)
    float v = accp + __shfl_xor(accp, 32, 64);
    if (half == 0) s_red[wid][row] = fmaf(g3bias, wsum, v);
    __syncthreads();
    if (tid < 32) {
        float sum = s_red[0][tid] + s_red[1][tid] + s_red[2][tid] + s_red[3][tid];
        ucp[(nh*B + b)*P_TOTAL + p0 + tid] = sum * (1.0f/NBC);
    }
}

// ---------------------------------------------------------------------------
// Kernel C: combine n-quarter partials + bilinear align_corners upsample
// ---------------------------------------------------------------------------
__global__ void bg_upsample(const float* __restrict__ ucp, float* __restrict__ out) {
    int idx = blockIdx.x * 256 + threadIdx.x;
    if (idx >= B*HOUT*WOUT) return;
    int x = idx & (WOUT-1);
    int y = (idx >> 8) & (HOUT-1);
    int b = idx >> 16;
    float fy = (float)y * ((float)(HC-1)/(float)(HOUT-1));
    float fx = (float)x * ((float)(WC-1)/(float)(WOUT-1));
    int y0 = (int)floorf(fy);
    int x0 = (int)floorf(fx);
    int y1 = min(y0+1, HC-1);
    int x1 = min(x0+1, WC-1);
    float wy = fy - (float)y0;
    float wx = fx - (float)x0;
    float v00 = 0.0f, v01 = 0.0f, v10 = 0.0f, v11 = 0.0f;
    #pragma unroll
    for (int q = 0; q < NSPLIT; ++q) {
        const float* u = ucp + (q*B + b)*P_TOTAL;
        v00 += u[y0*WC+x0];
        v01 += u[y0*WC+x1];
        v10 += u[y1*WC+x0];
        v11 += u[y1*WC+x1];
    }
    float top = v00 + (v01 - v00)*wx;
    float bot = v10 + (v11 - v10)*wx;
    out[idx] = top + (bot - top)*wy;
}

extern "C" void kernel_launch(void* const* d_in, const int* in_sizes, int n_in,
                              void* d_out, int out_size, void* d_ws, size_t ws_size,
                              hipStream_t stream) {
    const float* bi  = (const float*)d_in[0];
    const float* e1w = (const float*)d_in[2];
    const float* e1b = (const float*)d_in[3];
    const float* e2w = (const float*)d_in[4];
    const float* e2b = (const float*)d_in[5];
    const float* g1w = (const float*)d_in[6];
    const float* g1b = (const float*)d_in[7];
    const float* g2w = (const float*)d_in[8];
    const float* g2b = (const float*)d_in[9];
    const float* g3w = (const float*)d_in[10];
    const float* g3b = (const float*)d_in[11];
    const float* ds  = (const float*)d_in[12];
    float* out = (float*)d_out;

    float* bfg = (float*)d_ws;                          // 128 KB (x128 scaled)
    float* ucp = bfg + B*NBC*HID;                       // 256 KB partials
    unsigned short* lutg = (unsigned short*)(ucp + NSPLIT*B*P_TOTAL);  // 8 KB
    float* cg_g = (float*)(lutg + 4096);                // 1 MB cg table

    bg_prep<<<dim3(514 + P_TOTAL/4), dim3(64), 0, stream>>>(
        bi, e1w, e1b, e2w, e2b, g1w, g1b, bfg, lutg, cg_g);
    bg_main<<<dim3(P_TOTAL/32, B, NSPLIT), dim3(256), 0, stream>>>(
        bi, g1w, g2w, g2b, g3w, g3b, ds, bfg, lutg, cg_g, ucp);
    bg_upsample<<<dim3((B*HOUT*WOUT)/256), dim3(256), 0, stream>>>(ucp, out);
}